// Round 13
// baseline (142.831 us; speedup 1.0000x reference)
//
#include <hip/hip_runtime.h>

// GCN layer: out = A_norm @ (h @ W^T + b), A_norm = D^-1/2 (A + I) D^-1/2
// Inputs: h [N,128] f32, W [128,128] f32, b [128] f32, edges [2,E] int32
// Output: [N,128] f32
//
// R21: model now closes: agg ~44.5 (plateau, 5 variants), binB_cv ~6,
//      binA ~6, gemm128-STAGED ~27 but gemm-DIRECT-A ~38 (load_a8 does
//      32B loads at 512B stride = 16 lines per 16 lanes, ~4x over-fetch;
//      staging coalesces). R18's fused k_gb(44) = binA(6)+gemm_direct(38).
//      Assemble best-measured variant of each stage:
//        k_binA (R19, standalone tiny-LDS, 6)
//        k_gemm (R13 staged A+B 128-tile, unscaled epilogue, 27)
//        k_binB (R18 cell-vectorized, 6)
//        k_agg  (R18 8-deep half-wave, 44.5)
//      Predicted: 44 fill + 83.5 = ~127-131.

#define IN_DIM 128
#define OUT_DIM 128
#define CAP 40    // ELL capacity/node; P(deg>40 | Poisson(16)) ~ 3e-7
#define NB_A 256  // pass-A blocks (= cells per bin in pass B)
#define NBIN 784  // dst bins (d>>6); 784*64 = 50176 >= n
#define BINW 64   // nodes per bin
#define CAPA 16   // per-(block,bin) record capacity; lambda=4.0/cell
#define OVB 8     // per-passA-block overflow slots
#define OVCAP 4096

typedef short bf16x8 __attribute__((ext_vector_type(8)));
typedef float f32x4 __attribute__((ext_vector_type(4)));
typedef unsigned short us8 __attribute__((ext_vector_type(8)));
typedef unsigned short us4 __attribute__((ext_vector_type(4)));

__device__ __forceinline__ unsigned short f2bf(float f) {
    unsigned u = __float_as_uint(f);
    u += 0x7fffu + ((u >> 16) & 1u);  // round-nearest-even
    return (unsigned short)(u >> 16);
}
__device__ __forceinline__ float bf2f(unsigned short s) {
    return __uint_as_float(((unsigned)s) << 16);
}
__device__ __forceinline__ void accw(float4& acc, ushort4 v, float wt) {
    acc.x += wt * bf2f(v.x);
    acc.y += wt * bf2f(v.y);
    acc.z += wt * bf2f(v.z);
    acc.w += wt * bf2f(v.w);
}

// ---- D1: binA edge binning (dst>>6), standalone, tiny LDS ----
__global__ __launch_bounds__(256) void k_binA(const int* __restrict__ ed,
                                              unsigned* __restrict__ gbuf,
                                              int* __restrict__ gcnt,
                                              int* __restrict__ aovb,
                                              int2* __restrict__ aov,
                                              int* __restrict__ ctrs, int E) {
    __shared__ int bc[NBIN];  // 3.1 KB
    __shared__ int ovc;
    __shared__ int2 ovl[OVB];
    const int tid = threadIdx.x;
    const int blk = blockIdx.x;
    if (blk == 0 && tid == 0) ctrs[0] = 0;  // ovf2c for D3/D4 (plain store)
    for (int i = tid; i < NBIN; i += 256) bc[i] = 0;
    if (tid == 0) ovc = 0;
    __syncthreads();
    const int chunk = (E + NB_A - 1) / NB_A;
    const int e0 = blk * chunk, e1 = min(E, e0 + chunk);
    for (int e = e0 + tid; e < e1; e += 256) {
        int s = ed[e];
        int d = ed[E + e];
        int bin = d >> 6, dlo = d & 63;
        int r = atomicAdd(&bc[bin], 1);  // LDS atomic
        if (r < CAPA) {
            gbuf[((size_t)blk * NBIN + bin) * CAPA + r] =
                (unsigned)s | ((unsigned)dlo << 16);
        } else {
            int k = atomicAdd(&ovc, 1);  // LDS atomic
            if (k < OVB) ovl[k] = make_int2(s, d);
        }
    }
    __syncthreads();
    for (int i = tid; i < NBIN; i += 256)
        gcnt[(size_t)blk * NBIN + i] = min(bc[i], CAPA);
    int nov = min(ovc, OVB);
    if (tid < nov) aov[blk * OVB + tid] = ovl[tid];
    if (tid == 0) aovb[blk] = nov;  // plain store -> no memset dispatch
}

// ---- D2: MFMA linear, 128x128 tile, STAGED A and B (coalesced f32->bf16).
//          hs = bf16(h@W^T + b), unscaled; rs applied in f32 at agg. ----
__global__ __launch_bounds__(256) void k_gemm(
        const float* __restrict__ h, const float* __restrict__ W,
        const float* __restrict__ b, unsigned short* __restrict__ hsb, int n) {
    __shared__ unsigned short sA[128 * 136];  // 34.8 KB (+8 pad)
    __shared__ unsigned short sB[128 * 136];  // 34.8 KB

    const int tid = threadIdx.x;
    const int lane = tid & 63;
    const int wv = tid >> 6;
    const int quad = lane >> 4;
    const int l16 = lane & 15;
    const int row0 = blockIdx.x * 128;

    {
        const float4* h4 = (const float4*)h;
        const float4* W4 = (const float4*)W;
        for (int t = tid; t < 128 * 32; t += 256) {
            int r = t >> 5, c4 = t & 31;
            int row = row0 + r;
            float4 v = make_float4(0.f, 0.f, 0.f, 0.f);
            if (row < n) v = h4[(size_t)row * 32 + c4];
            ushort4 p;
            p.x = f2bf(v.x); p.y = f2bf(v.y); p.z = f2bf(v.z); p.w = f2bf(v.w);
            ((ushort4*)sA)[r * 34 + c4] = p;  // 136/4 = 34
            float4 w = W4[t];
            ushort4 q;
            q.x = f2bf(w.x); q.y = f2bf(w.y); q.z = f2bf(w.z); q.w = f2bf(w.w);
            ((ushort4*)sB)[(t >> 5) * 34 + (t & 31)] = q;
        }
    }
    __syncthreads();

    f32x4 acc[2][8];
#pragma unroll
    for (int mt = 0; mt < 2; ++mt)
#pragma unroll
        for (int nt = 0; nt < 8; ++nt) acc[mt][nt] = (f32x4){0.f, 0.f, 0.f, 0.f};

    const int koff = quad * 8;
#pragma unroll
    for (int kc = 0; kc < 4; ++kc) {
        int kbase = kc * 32 + koff;
        bf16x8 a0 = *(const bf16x8*)(sA + (wv * 32 + 0 + l16) * 136 + kbase);
        bf16x8 a1 = *(const bf16x8*)(sA + (wv * 32 + 16 + l16) * 136 + kbase);
#pragma unroll
        for (int nt = 0; nt < 8; ++nt) {
            bf16x8 bb = *(const bf16x8*)(sB + (nt * 16 + l16) * 136 + kbase);
            acc[0][nt] = __builtin_amdgcn_mfma_f32_16x16x32_bf16(a0, bb, acc[0][nt], 0, 0, 0);
            acc[1][nt] = __builtin_amdgcn_mfma_f32_16x16x32_bf16(a1, bb, acc[1][nt], 0, 0, 0);
        }
    }

    // epilogue: bias, bf16 store (unscaled)
#pragma unroll
    for (int mt = 0; mt < 2; ++mt) {
#pragma unroll
        for (int r = 0; r < 4; ++r) {
            int row = row0 + wv * 32 + mt * 16 + quad * 4 + r;
            if (row >= n) continue;
#pragma unroll
            for (int nt = 0; nt < 8; ++nt) {
                int col = nt * 16 + l16;
                hsb[(size_t)row * 128 + col] = f2bf(acc[mt][nt][r] + b[col]);
            }
        }
    }
}

// ---- D3: one block per 64-node bin; cell-per-thread with vectorized cell
//          load (4 independent int4), records processed from registers. ----
__global__ __launch_bounds__(256) void k_binB(const unsigned* __restrict__ gbuf,
                                              const int* __restrict__ gcnt,
                                              const int* __restrict__ aovb,
                                              const int2* __restrict__ aov,
                                              unsigned short* __restrict__ ell,
                                              int* __restrict__ cnt,
                                              float* __restrict__ rs,
                                              int2* __restrict__ ovf2,
                                              int* __restrict__ ovf2c, int n) {
    __shared__ int lcnt[BINW];
    __shared__ __align__(16) unsigned short ells[BINW * CAP];  // 5 KB
    const int tid = threadIdx.x;
    const int bin = blockIdx.x;
    const int node0 = bin * BINW;

    if (tid < BINW) lcnt[tid] = 0;
    __syncthreads();

    // thread t consumes pass-A block t's 64B cell (vector-loaded, no serial chain)
    {
        int c = gcnt[(size_t)tid * NBIN + bin];
        const int4* cell4 = (const int4*)(gbuf + ((size_t)tid * NBIN + bin) * CAPA);
        int4 q0 = cell4[0];  // 4 independent loads, all in flight together
        int4 q1 = cell4[1];
        int4 q2 = cell4[2];
        int4 q3 = cell4[3];
#define PROC(REC, J)                                              \
        if ((J) < c) {                                            \
            unsigned rec = (unsigned)(REC);                       \
            int src = rec & 0xffff;                               \
            int dlo = rec >> 16;                                  \
            int r = atomicAdd(&lcnt[dlo], 1);                     \
            if (r < CAP) {                                        \
                ells[dlo * CAP + r] = (unsigned short)src;        \
            } else {                                              \
                int k = atomicAdd(ovf2c, 1);                      \
                if (k < OVCAP) ovf2[k] = make_int2(src, node0 + dlo); \
            }                                                     \
        }
        PROC(q0.x, 0)  PROC(q0.y, 1)  PROC(q0.z, 2)  PROC(q0.w, 3)
        PROC(q1.x, 4)  PROC(q1.y, 5)  PROC(q1.z, 6)  PROC(q1.w, 7)
        PROC(q2.x, 8)  PROC(q2.y, 9)  PROC(q2.z, 10) PROC(q2.w, 11)
        PROC(q3.x, 12) PROC(q3.y, 13) PROC(q3.z, 14) PROC(q3.w, 15)
#undef PROC
    }
    // merge pass-A per-block overflow slots (expected ~0 on this graph)
    {
        int cov = aovb[tid];  // tid = passA block id (NB_A == 256)
        for (int j = 0; j < cov; ++j) {
            int2 p = aov[tid * OVB + j];
            if ((p.y >> 6) == bin) {
                int dlo = p.y & 63;
                int r = atomicAdd(&lcnt[dlo], 1);
                if (r < CAP) {
                    ells[dlo * CAP + r] = (unsigned short)p.x;
                } else {
                    int k = atomicAdd(ovf2c, 1);
                    if (k < OVCAP) ovf2[k] = make_int2(p.x, node0 + dlo);
                }
            }
        }
    }
    __syncthreads();
    // coalesced write-out: degrees + rs + 5KB of ELL rows
    if (tid < BINW) {
        int node = node0 + tid;
        if (node < n) {
            cnt[node] = lcnt[tid];
            rs[node] = rsqrtf((float)(lcnt[tid] + 1));
        }
    }
    const int4* sp = (const int4*)ells;
    int4* dp = (int4*)(ell + (size_t)node0 * CAP);
#pragma unroll
    for (int i = tid; i < BINW * CAP * 2 / 16; i += 256) dp[i] = sp[i];
}

// ---- D4: half-wave (32 lanes) per node; lane = 4 channels (ushort4 = 8B).
// out[d] = rs_d * ( rs_d*g_d + sum_{s in N(d)} rs_s*g_s ), g = hs (unscaled).
__global__ __launch_bounds__(256) void k_agg(const int* __restrict__ cnt,
                                             const float* __restrict__ rs,
                                             const unsigned short* __restrict__ ell,
                                             const int2* __restrict__ ovf2,
                                             const int* __restrict__ ovf2c,
                                             const unsigned short* __restrict__ hsb,
                                             float* __restrict__ out, int n) {
    int node = blockIdx.x * 8 + (threadIdx.x >> 5);
    if (node >= n) return;
    int lane = threadIdx.x & 31;
    int deg = cnt[node];
    float rsn = rs[node];
    int m = min(deg, CAP);

    const ushort4* hp = (const ushort4*)hsb;  // row = 32 ushort4 (256B)
    ushort4 sv = hp[(size_t)node * 32 + lane];
    float4 acc;
    acc.x = rsn * bf2f(sv.x); acc.y = rsn * bf2f(sv.y);
    acc.z = rsn * bf2f(sv.z); acc.w = rsn * bf2f(sv.w);

    const unsigned short* row = ell + (size_t)node * CAP;  // 80B/node, 16B-aligned
    int e = 0;
    for (; e + 8 <= m; e += 8) {  // 16B index load + 8 rs + 8 row gathers in flight
        us8 p = *(const us8*)(row + e);
        float w0 = rs[p[0]], w1 = rs[p[1]], w2 = rs[p[2]], w3 = rs[p[3]];
        float w4 = rs[p[4]], w5 = rs[p[5]], w6 = rs[p[6]], w7 = rs[p[7]];
        ushort4 v0 = hp[(size_t)p[0] * 32 + lane];
        ushort4 v1 = hp[(size_t)p[1] * 32 + lane];
        ushort4 v2 = hp[(size_t)p[2] * 32 + lane];
        ushort4 v3 = hp[(size_t)p[3] * 32 + lane];
        ushort4 v4 = hp[(size_t)p[4] * 32 + lane];
        ushort4 v5 = hp[(size_t)p[5] * 32 + lane];
        ushort4 v6 = hp[(size_t)p[6] * 32 + lane];
        ushort4 v7 = hp[(size_t)p[7] * 32 + lane];
        accw(acc, v0, w0); accw(acc, v1, w1); accw(acc, v2, w2); accw(acc, v3, w3);
        accw(acc, v4, w4); accw(acc, v5, w5); accw(acc, v6, w6); accw(acc, v7, w7);
    }
    if (e + 4 <= m) {
        us4 p = *(const us4*)(row + e);
        float w0 = rs[p[0]], w1 = rs[p[1]], w2 = rs[p[2]], w3 = rs[p[3]];
        ushort4 v0 = hp[(size_t)p[0] * 32 + lane];
        ushort4 v1 = hp[(size_t)p[1] * 32 + lane];
        ushort4 v2 = hp[(size_t)p[2] * 32 + lane];
        ushort4 v3 = hp[(size_t)p[3] * 32 + lane];
        accw(acc, v0, w0); accw(acc, v1, w1); accw(acc, v2, w2); accw(acc, v3, w3);
        e += 4;
    }
    for (; e < m; ++e) {
        int s = row[e];
        accw(acc, hp[(size_t)s * 32 + lane], rs[s]);
    }
    if (deg > CAP) {  // expect: never taken
        int novf = min(*ovf2c, OVCAP);
        for (int i = 0; i < novf; ++i) {
            int2 p = ovf2[i];
            if (p.y == node) {
                accw(acc, hp[(size_t)p.x * 32 + lane], rs[p.x]);
            }
        }
    }
    acc.x *= rsn; acc.y *= rsn; acc.z *= rsn; acc.w *= rsn;
    ((float4*)out)[(size_t)node * 32 + lane] = acc;
}

extern "C" void kernel_launch(void* const* d_in, const int* in_sizes, int n_in,
                              void* d_out, int out_size, void* d_ws, size_t ws_size,
                              hipStream_t stream) {
    const float* h = (const float*)d_in[0];
    const float* W = (const float*)d_in[1];
    const float* b = (const float*)d_in[2];
    const int* edges = (const int*)d_in[3];

    const int n = in_sizes[0] / IN_DIM;  // 50000 (ushort records assume n < 65536)
    const int E = in_sizes[3] / 2;       // 800000
    const int ngemm = (n + 127) / 128;   // 391 GEMM tiles
    const int nnode_pad = NBIN * BINW;   // 50176

    // workspace carve-up (float units, each region 2KB-aligned)
    size_t o = 0;
    auto carve = [&](size_t elems) {
        size_t cur = o;
        o += (elems + 511) & ~(size_t)511;
        return cur;
    };
    float* ws = (float*)d_ws;
    unsigned short* hsb = (unsigned short*)(ws + carve((size_t)n * 64));  // n*128 bf16
    unsigned* gbuf = (unsigned*)(ws + carve((size_t)NB_A * NBIN * CAPA)); // 12.8 MB
    int* gcnt = (int*)(ws + carve((size_t)NB_A * NBIN));
    int* aovb = (int*)(ws + carve(NB_A));
    int2* aov = (int2*)(ws + carve((size_t)NB_A * OVB * 2));
    int* cnt = (int*)(ws + carve(nnode_pad));
    float* rs = ws + carve(nnode_pad);
    unsigned short* ell = (unsigned short*)(ws + carve((size_t)nnode_pad * CAP / 2));
    int2* ovf2 = (int2*)(ws + carve(OVCAP * 2));
    int* ctrs = (int*)(ws + carve(2));  // [0] = ovf2c

    float* out = (float*)d_out;

    k_binA<<<NB_A, 256, 0, stream>>>(edges, gbuf, gcnt, aovb, aov, ctrs, E);
    k_gemm<<<ngemm, 256, 0, stream>>>(h, W, b, hsb, n);
    k_binB<<<NBIN, 256, 0, stream>>>(gbuf, gcnt, aovb, aov, ell, cnt, rs,
                                     ovf2, ctrs, n);
    k_agg<<<(n + 7) / 8, 256, 0, stream>>>(cnt, rs, ell, ovf2, ctrs, hsb, out, n);
}

// Round 15
// 142.271 us; speedup vs baseline: 1.0039x; 1.0039x over previous
//
#include <hip/hip_runtime.h>

// GCN layer: out = A_norm @ (h @ W^T + b), A_norm = D^-1/2 (A + I) D^-1/2
// Inputs: h [N,128] f32, W [128,128] f32, b [128] f32, edges [2,E] int32
// Output: [N,128] f32
//
// R22 (resubmit; R14-round bench died on container infra, kernel never ran):
//      R19/R21 confirmed fusion's value is CONCURRENT INDEPENDENT WORK
//      (separate binA+gemm costs +4 vs R18's fused k_gb). Extend the one
//      proven lever: split R18's k_gb into two halves and hide binB under
//      the second half's gemm tiles (binB depends only on binA; gemm
//      depends on nothing):
//        D1: gemm tiles [0,196) || binA   (exact R18 code)
//        D2: gemm tiles [196,391) || binB (binB LDS unions into sB)
//        D3: agg (exact R18)
//      Bitwise-identical output to R18.

#define IN_DIM 128
#define OUT_DIM 128
#define CAP 40    // ELL capacity/node; P(deg>40 | Poisson(16)) ~ 3e-7
#define NB_A 256  // pass-A blocks (= cells per bin in pass B)
#define NBIN 784  // dst bins (d>>6); 784*64 = 50176 >= n
#define BINW 64   // nodes per bin
#define CAPA 16   // per-(block,bin) record capacity; lambda=4.0/cell
#define OVB 8     // per-passA-block overflow slots
#define OVCAP 4096

typedef short bf16x8 __attribute__((ext_vector_type(8)));
typedef float f32x4 __attribute__((ext_vector_type(4)));
typedef unsigned short us8 __attribute__((ext_vector_type(8)));
typedef unsigned short us4 __attribute__((ext_vector_type(4)));

__device__ __forceinline__ unsigned short f2bf(float f) {
    unsigned u = __float_as_uint(f);
    u += 0x7fffu + ((u >> 16) & 1u);  // round-nearest-even
    return (unsigned short)(u >> 16);
}
__device__ __forceinline__ float bf2f(unsigned short s) {
    return __uint_as_float(((unsigned)s) << 16);
}
__device__ __forceinline__ void accw(float4& acc, ushort4 v, float wt) {
    acc.x += wt * bf2f(v.x);
    acc.y += wt * bf2f(v.y);
    acc.z += wt * bf2f(v.z);
    acc.w += wt * bf2f(v.w);
}
__device__ __forceinline__ bf16x8 load_a8(const float* h, int row, int k0, int n) {
    bf16x8 r;
    if (row < n) {
        const float4* p = (const float4*)(h + (size_t)row * 128 + k0);
        float4 f0 = p[0], f1 = p[1];
        r[0] = (short)f2bf(f0.x); r[1] = (short)f2bf(f0.y);
        r[2] = (short)f2bf(f0.z); r[3] = (short)f2bf(f0.w);
        r[4] = (short)f2bf(f1.x); r[5] = (short)f2bf(f1.y);
        r[6] = (short)f2bf(f1.z); r[7] = (short)f2bf(f1.w);
    } else {
        r = (bf16x8){0, 0, 0, 0, 0, 0, 0, 0};
    }
    return r;
}

// Shared GEMM body: tile of 128 rows; B staged in sB, A direct from global
// (R18's measured-best variant).
__device__ __forceinline__ void gemm_body(
        unsigned short* sB, const float* __restrict__ h,
        const float* __restrict__ W, const float* __restrict__ b,
        unsigned short* __restrict__ hsb, int n, int tile) {
    const int tid = threadIdx.x;
    const int lane = tid & 63;
    const int wv = tid >> 6;
    const int quad = lane >> 4;
    const int l16 = lane & 15;
    const int row0 = tile * 128;

    {
        const float4* W4 = (const float4*)W;
        for (int t = tid; t < 128 * 32; t += 256) {
            float4 w = W4[t];
            ushort4 q;
            q.x = f2bf(w.x); q.y = f2bf(w.y); q.z = f2bf(w.z); q.w = f2bf(w.w);
            ((ushort4*)sB)[(t >> 5) * 34 + (t & 31)] = q;  // 136/4 = 34
        }
    }
    __syncthreads();

    f32x4 acc[2][8];
#pragma unroll
    for (int mt = 0; mt < 2; ++mt)
#pragma unroll
        for (int nt = 0; nt < 8; ++nt) acc[mt][nt] = (f32x4){0.f, 0.f, 0.f, 0.f};

    const int koff = quad * 8;
    const int ra0 = row0 + wv * 32 + l16;
    const int ra1 = ra0 + 16;
#pragma unroll
    for (int kc = 0; kc < 4; ++kc) {
        int kbase = kc * 32 + koff;
        bf16x8 a0 = load_a8(h, ra0, kbase, n);
        bf16x8 a1 = load_a8(h, ra1, kbase, n);
#pragma unroll
        for (int nt = 0; nt < 8; ++nt) {
            bf16x8 bb = *(const bf16x8*)(sB + (nt * 16 + l16) * 136 + kbase);
            acc[0][nt] = __builtin_amdgcn_mfma_f32_16x16x32_bf16(a0, bb, acc[0][nt], 0, 0, 0);
            acc[1][nt] = __builtin_amdgcn_mfma_f32_16x16x32_bf16(a1, bb, acc[1][nt], 0, 0, 0);
        }
    }

    // epilogue: bias, bf16 store (unscaled; rs applied in f32 at agg)
#pragma unroll
    for (int mt = 0; mt < 2; ++mt) {
#pragma unroll
        for (int r = 0; r < 4; ++r) {
            int row = row0 + wv * 32 + mt * 16 + quad * 4 + r;
            if (row >= n) continue;
#pragma unroll
            for (int nt = 0; nt < 8; ++nt) {
                int col = nt * 16 + l16;
                hsb[(size_t)row * 128 + col] = f2bf(acc[mt][nt][r] + b[col]);
            }
        }
    }
}

// ---- D1: blocks [0,ng1) = gemm tiles [0,ng1); blocks [ng1,+NB_A) = binA ----
__global__ __launch_bounds__(256) void k_gb1(
        const float* __restrict__ h, const float* __restrict__ W,
        const float* __restrict__ b, unsigned short* __restrict__ hsb, int n,
        const int* __restrict__ ed, unsigned* __restrict__ gbuf,
        int* __restrict__ gcnt, int* __restrict__ aovb, int2* __restrict__ aov,
        int* __restrict__ ctrs, int E, int ng1) {
    __shared__ __align__(16) unsigned short sB[128 * 136];  // 34.8KB; union: binA bc[]
    __shared__ int ovc;
    __shared__ int2 ovl[OVB];
    const int tid = threadIdx.x;

    if ((int)blockIdx.x >= ng1) {
        // ---- binA: bin edges by dst>>6 into private per-(block,bin) cells ----
        int blk = blockIdx.x - ng1;
        if (blk == 0 && tid == 0) ctrs[0] = 0;  // ovf2c (plain store)
        int* bc = (int*)sB;                     // NBIN counters (3.1KB of sB)
        for (int i = tid; i < NBIN; i += 256) bc[i] = 0;
        if (tid == 0) ovc = 0;
        __syncthreads();
        const int chunk = (E + NB_A - 1) / NB_A;
        const int e0 = blk * chunk, e1 = min(E, e0 + chunk);
        for (int e = e0 + tid; e < e1; e += 256) {
            int s = ed[e];
            int d = ed[E + e];
            int bin = d >> 6, dlo = d & 63;
            int r = atomicAdd(&bc[bin], 1);  // LDS atomic
            if (r < CAPA) {
                gbuf[((size_t)blk * NBIN + bin) * CAPA + r] =
                    (unsigned)s | ((unsigned)dlo << 16);
            } else {
                int k = atomicAdd(&ovc, 1);  // LDS atomic
                if (k < OVB) ovl[k] = make_int2(s, d);
            }
        }
        __syncthreads();
        for (int i = tid; i < NBIN; i += 256)
            gcnt[(size_t)blk * NBIN + i] = min(bc[i], CAPA);
        int nov = min(ovc, OVB);
        if (tid < nov) aov[blk * OVB + tid] = ovl[tid];
        if (tid == 0) aovb[blk] = nov;  // plain store -> no memset dispatch
        return;
    }
    gemm_body(sB, h, W, b, hsb, n, blockIdx.x);
}

// ---- D2: blocks [0,ng2) = gemm tiles [tile0,tile0+ng2); blocks [ng2,+NBIN)
//          = binB (cell-per-thread, vectorized cell load; LDS unions sB) ----
__global__ __launch_bounds__(256) void k_gb2(
        const float* __restrict__ h, const float* __restrict__ W,
        const float* __restrict__ b, unsigned short* __restrict__ hsb, int n,
        const unsigned* __restrict__ gbuf, const int* __restrict__ gcnt,
        const int* __restrict__ aovb, const int2* __restrict__ aov,
        unsigned short* __restrict__ ell, int* __restrict__ cnt,
        float* __restrict__ rs, int2* __restrict__ ovf2,
        int* __restrict__ ovf2c, int tile0, int ng2) {
    __shared__ __align__(16) unsigned short sB[128 * 136];  // 34.8KB; union: binB
    const int tid = threadIdx.x;

    if ((int)blockIdx.x >= ng2) {
        // ---- binB: lcnt = first 64 ints of sB; ells at +128 ushorts (16B-aligned) ----
        const int bin = blockIdx.x - ng2;
        const int node0 = bin * BINW;
        int* lcnt = (int*)sB;
        unsigned short* ells = sB + 128;

        if (tid < BINW) lcnt[tid] = 0;
        __syncthreads();

        {
            int c = gcnt[(size_t)tid * NBIN + bin];
            const int4* cell4 = (const int4*)(gbuf + ((size_t)tid * NBIN + bin) * CAPA);
            int4 q0 = cell4[0];  // 4 independent loads, all in flight together
            int4 q1 = cell4[1];
            int4 q2 = cell4[2];
            int4 q3 = cell4[3];
#define PROC(REC, J)                                              \
            if ((J) < c) {                                        \
                unsigned rec = (unsigned)(REC);                   \
                int src = rec & 0xffff;                           \
                int dlo = rec >> 16;                              \
                int r = atomicAdd(&lcnt[dlo], 1);                 \
                if (r < CAP) {                                    \
                    ells[dlo * CAP + r] = (unsigned short)src;    \
                } else {                                          \
                    int k = atomicAdd(ovf2c, 1);                  \
                    if (k < OVCAP) ovf2[k] = make_int2(src, node0 + dlo); \
                }                                                 \
            }
            PROC(q0.x, 0)  PROC(q0.y, 1)  PROC(q0.z, 2)  PROC(q0.w, 3)
            PROC(q1.x, 4)  PROC(q1.y, 5)  PROC(q1.z, 6)  PROC(q1.w, 7)
            PROC(q2.x, 8)  PROC(q2.y, 9)  PROC(q2.z, 10) PROC(q2.w, 11)
            PROC(q3.x, 12) PROC(q3.y, 13) PROC(q3.z, 14) PROC(q3.w, 15)
#undef PROC
        }
        // merge pass-A per-block overflow slots (expected ~0 on this graph)
        {
            int cov = aovb[tid];  // tid = passA block id (NB_A == 256)
            for (int j = 0; j < cov; ++j) {
                int2 p = aov[tid * OVB + j];
                if ((p.y >> 6) == bin) {
                    int dlo = p.y & 63;
                    int r = atomicAdd(&lcnt[dlo], 1);
                    if (r < CAP) {
                        ells[dlo * CAP + r] = (unsigned short)p.x;
                    } else {
                        int k = atomicAdd(ovf2c, 1);
                        if (k < OVCAP) ovf2[k] = make_int2(p.x, node0 + dlo);
                    }
                }
            }
        }
        __syncthreads();
        // coalesced write-out: degrees + rs + 5KB of ELL rows
        if (tid < BINW) {
            int node = node0 + tid;
            cnt[node] = lcnt[tid];
            rs[node] = rsqrtf((float)(lcnt[tid] + 1));
        }
        const int4* sp = (const int4*)ells;
        int4* dp = (int4*)(ell + (size_t)node0 * CAP);
#pragma unroll
        for (int i = tid; i < BINW * CAP * 2 / 16; i += 256) dp[i] = sp[i];
        return;
    }
    gemm_body(sB, h, W, b, hsb, n, tile0 + blockIdx.x);
}

// ---- D3: half-wave (32 lanes) per node; lane = 4 channels (ushort4 = 8B).
// out[d] = rs_d * ( rs_d*g_d + sum_{s in N(d)} rs_s*g_s ), g = hs (unscaled).
__global__ __launch_bounds__(256) void k_agg(const int* __restrict__ cnt,
                                             const float* __restrict__ rs,
                                             const unsigned short* __restrict__ ell,
                                             const int2* __restrict__ ovf2,
                                             const int* __restrict__ ovf2c,
                                             const unsigned short* __restrict__ hsb,
                                             float* __restrict__ out, int n) {
    int node = blockIdx.x * 8 + (threadIdx.x >> 5);
    if (node >= n) return;
    int lane = threadIdx.x & 31;
    int deg = cnt[node];
    float rsn = rs[node];
    int m = min(deg, CAP);

    const ushort4* hp = (const ushort4*)hsb;  // row = 32 ushort4 (256B)
    ushort4 sv = hp[(size_t)node * 32 + lane];
    float4 acc;
    acc.x = rsn * bf2f(sv.x); acc.y = rsn * bf2f(sv.y);
    acc.z = rsn * bf2f(sv.z); acc.w = rsn * bf2f(sv.w);

    const unsigned short* row = ell + (size_t)node * CAP;  // 80B/node, 16B-aligned
    int e = 0;
    for (; e + 8 <= m; e += 8) {  // 16B index load + 8 rs + 8 row gathers in flight
        us8 p = *(const us8*)(row + e);
        float w0 = rs[p[0]], w1 = rs[p[1]], w2 = rs[p[2]], w3 = rs[p[3]];
        float w4 = rs[p[4]], w5 = rs[p[5]], w6 = rs[p[6]], w7 = rs[p[7]];
        ushort4 v0 = hp[(size_t)p[0] * 32 + lane];
        ushort4 v1 = hp[(size_t)p[1] * 32 + lane];
        ushort4 v2 = hp[(size_t)p[2] * 32 + lane];
        ushort4 v3 = hp[(size_t)p[3] * 32 + lane];
        ushort4 v4 = hp[(size_t)p[4] * 32 + lane];
        ushort4 v5 = hp[(size_t)p[5] * 32 + lane];
        ushort4 v6 = hp[(size_t)p[6] * 32 + lane];
        ushort4 v7 = hp[(size_t)p[7] * 32 + lane];
        accw(acc, v0, w0); accw(acc, v1, w1); accw(acc, v2, w2); accw(acc, v3, w3);
        accw(acc, v4, w4); accw(acc, v5, w5); accw(acc, v6, w6); accw(acc, v7, w7);
    }
    if (e + 4 <= m) {
        us4 p = *(const us4*)(row + e);
        float w0 = rs[p[0]], w1 = rs[p[1]], w2 = rs[p[2]], w3 = rs[p[3]];
        ushort4 v0 = hp[(size_t)p[0] * 32 + lane];
        ushort4 v1 = hp[(size_t)p[1] * 32 + lane];
        ushort4 v2 = hp[(size_t)p[2] * 32 + lane];
        ushort4 v3 = hp[(size_t)p[3] * 32 + lane];
        accw(acc, v0, w0); accw(acc, v1, w1); accw(acc, v2, w2); accw(acc, v3, w3);
        e += 4;
    }
    for (; e < m; ++e) {
        int s = row[e];
        accw(acc, hp[(size_t)s * 32 + lane], rs[s]);
    }
    if (deg > CAP) {  // expect: never taken
        int novf = min(*ovf2c, OVCAP);
        for (int i = 0; i < novf; ++i) {
            int2 p = ovf2[i];
            if (p.y == node) {
                accw(acc, hp[(size_t)p.x * 32 + lane], rs[p.x]);
            }
        }
    }
    acc.x *= rsn; acc.y *= rsn; acc.z *= rsn; acc.w *= rsn;
    ((float4*)out)[(size_t)node * 32 + lane] = acc;
}

extern "C" void kernel_launch(void* const* d_in, const int* in_sizes, int n_in,
                              void* d_out, int out_size, void* d_ws, size_t ws_size,
                              hipStream_t stream) {
    const float* h = (const float*)d_in[0];
    const float* W = (const float*)d_in[1];
    const float* b = (const float*)d_in[2];
    const int* edges = (const int*)d_in[3];

    const int n = in_sizes[0] / IN_DIM;  // 50000 (ushort records assume n < 65536)
    const int E = in_sizes[3] / 2;       // 800000
    const int ngemm = (n + 127) / 128;   // 391 GEMM tiles
    const int ng1 = (ngemm + 1) / 2;     // 196 tiles in D1
    const int ng2 = ngemm - ng1;         // 195 tiles in D2
    const int nnode_pad = NBIN * BINW;   // 50176

    // workspace carve-up (float units, each region 2KB-aligned)
    size_t o = 0;
    auto carve = [&](size_t elems) {
        size_t cur = o;
        o += (elems + 511) & ~(size_t)511;
        return cur;
    };
    float* ws = (float*)d_ws;
    unsigned short* hsb = (unsigned short*)(ws + carve((size_t)n * 64));  // n*128 bf16
    unsigned* gbuf = (unsigned*)(ws + carve((size_t)NB_A * NBIN * CAPA)); // 12.8 MB
    int* gcnt = (int*)(ws + carve((size_t)NB_A * NBIN));
    int* aovb = (int*)(ws + carve(NB_A));
    int2* aov = (int2*)(ws + carve((size_t)NB_A * OVB * 2));
    int* cnt = (int*)(ws + carve(nnode_pad));
    float* rs = ws + carve(nnode_pad);
    unsigned short* ell = (unsigned short*)(ws + carve((size_t)nnode_pad * CAP / 2));
    int2* ovf2 = (int2*)(ws + carve(OVCAP * 2));
    int* ctrs = (int*)(ws + carve(2));  // [0] = ovf2c

    float* out = (float*)d_out;

    k_gb1<<<ng1 + NB_A, 256, 0, stream>>>(h, W, b, hsb, n, edges, gbuf, gcnt,
                                          aovb, aov, ctrs, E, ng1);
    k_gb2<<<ng2 + NBIN, 256, 0, stream>>>(h, W, b, hsb, n, gbuf, gcnt, aovb,
                                          aov, ell, cnt, rs, ovf2, ctrs,
                                          ng1, ng2);
    k_agg<<<(n + 7) / 8, 256, 0, stream>>>(cnt, rs, ell, ovf2, ctrs, hsb, out, n);
}

// Round 16
// 136.568 us; speedup vs baseline: 1.0459x; 1.0418x over previous
//
#include <hip/hip_runtime.h>

// GCN layer: out = A_norm @ (h @ W^T + b), A_norm = D^-1/2 (A + I) D^-1/2
// Inputs: h [N,128] f32, W [128,128] f32, b [128] f32, edges [2,E] int32
// Output: [N,128] f32
//
// R23: R18 (138.5, best of 9 compositions) with ONE change: k_gb's GEMM
//      half stages A in LDS (68KB total, 2 blocks/CU) instead of direct-A
//      global loads (which over-fetch 4x: 32B loads at 512B stride).
//      R11's "don't fuse scatter with big-LDS GEMM" applied to the
//      ticket-scatter fill (random 2-4B writes, latency-chained); binA is
//      NOT that: its writes are block-private contiguous 50KB cell regions
//      (L2-resident full-line fills). Betting binA tolerates 2 blocks/CU.
//      Per-row numerics identical to R18 (same f32->bf16 point, K-order).
//      Pipeline: k_gb (staged-gemm || binA) -> k_binB -> k_agg.

#define IN_DIM 128
#define OUT_DIM 128
#define CAP 40    // ELL capacity/node; P(deg>40 | Poisson(16)) ~ 3e-7
#define NB_A 256  // pass-A blocks (= cells per bin in pass B)
#define NBIN 784  // dst bins (d>>6); 784*64 = 50176 >= n
#define BINW 64   // nodes per bin
#define CAPA 16   // per-(block,bin) record capacity; lambda=4.0/cell
#define OVB 8     // per-passA-block overflow slots
#define OVCAP 4096

typedef short bf16x8 __attribute__((ext_vector_type(8)));
typedef float f32x4 __attribute__((ext_vector_type(4)));
typedef unsigned short us8 __attribute__((ext_vector_type(8)));
typedef unsigned short us4 __attribute__((ext_vector_type(4)));

__device__ __forceinline__ unsigned short f2bf(float f) {
    unsigned u = __float_as_uint(f);
    u += 0x7fffu + ((u >> 16) & 1u);  // round-nearest-even
    return (unsigned short)(u >> 16);
}
__device__ __forceinline__ float bf2f(unsigned short s) {
    return __uint_as_float(((unsigned)s) << 16);
}
__device__ __forceinline__ void accw(float4& acc, ushort4 v, float wt) {
    acc.x += wt * bf2f(v.x);
    acc.y += wt * bf2f(v.y);
    acc.z += wt * bf2f(v.z);
    acc.w += wt * bf2f(v.w);
}

// ---- D1: blocks [0,ngemm) = MFMA linear, STAGED A+B (128x128 tile, 68KB);
//          blocks [ngemm,+NB_A) = binA edge binning (dst>>6). ----
__global__ __launch_bounds__(256) void k_gb(
        const float* __restrict__ h, const float* __restrict__ W,
        const float* __restrict__ b, unsigned short* __restrict__ hsb, int n,
        const int* __restrict__ ed, unsigned* __restrict__ gbuf,
        int* __restrict__ gcnt, int* __restrict__ aovb, int2* __restrict__ aov,
        int* __restrict__ ctrs, int E, int ngemm) {
    __shared__ __align__(16) unsigned short sA[128 * 136];  // 34.8KB; union: binA bc[]
    __shared__ __align__(16) unsigned short sB[128 * 136];  // 34.8KB
    __shared__ int ovc;
    __shared__ int2 ovl[OVB];
    const int tid = threadIdx.x;

    if ((int)blockIdx.x >= ngemm) {
        // ---- binA: bin edges by dst>>6 into private per-(block,bin) cells ----
        int blk = blockIdx.x - ngemm;
        if (blk == 0 && tid == 0) ctrs[0] = 0;  // ovf2c (plain store)
        int* bc = (int*)sA;                     // NBIN counters (3.1KB of sA)
        for (int i = tid; i < NBIN; i += 256) bc[i] = 0;
        if (tid == 0) ovc = 0;
        __syncthreads();
        const int chunk = (E + NB_A - 1) / NB_A;
        const int e0 = blk * chunk, e1 = min(E, e0 + chunk);
        for (int e = e0 + tid; e < e1; e += 256) {
            int s = ed[e];
            int d = ed[E + e];
            int bin = d >> 6, dlo = d & 63;
            int r = atomicAdd(&bc[bin], 1);  // LDS atomic
            if (r < CAPA) {
                gbuf[((size_t)blk * NBIN + bin) * CAPA + r] =
                    (unsigned)s | ((unsigned)dlo << 16);
            } else {
                int k = atomicAdd(&ovc, 1);  // LDS atomic
                if (k < OVB) ovl[k] = make_int2(s, d);
            }
        }
        __syncthreads();
        for (int i = tid; i < NBIN; i += 256)
            gcnt[(size_t)blk * NBIN + i] = min(bc[i], CAPA);
        int nov = min(ovc, OVB);
        if (tid < nov) aov[blk * OVB + tid] = ovl[tid];
        if (tid == 0) aovb[blk] = nov;  // plain store -> no memset dispatch
        return;
    }

    // ---- MFMA linear: hs = bf16(h@W^T + b); A and B staged (coalesced) ----
    const int lane = tid & 63;
    const int wv = tid >> 6;
    const int quad = lane >> 4;
    const int l16 = lane & 15;
    const int row0 = blockIdx.x * 128;

    {
        const float4* h4 = (const float4*)h;
        const float4* W4 = (const float4*)W;
        for (int t = tid; t < 128 * 32; t += 256) {
            int r = t >> 5, c4 = t & 31;
            int row = row0 + r;
            float4 v = make_float4(0.f, 0.f, 0.f, 0.f);
            if (row < n) v = h4[(size_t)row * 32 + c4];
            ushort4 p;
            p.x = f2bf(v.x); p.y = f2bf(v.y); p.z = f2bf(v.z); p.w = f2bf(v.w);
            ((ushort4*)sA)[r * 34 + c4] = p;  // 136/4 = 34
            float4 w = W4[t];
            ushort4 q;
            q.x = f2bf(w.x); q.y = f2bf(w.y); q.z = f2bf(w.z); q.w = f2bf(w.w);
            ((ushort4*)sB)[(t >> 5) * 34 + (t & 31)] = q;
        }
    }
    __syncthreads();

    f32x4 acc[2][8];
#pragma unroll
    for (int mt = 0; mt < 2; ++mt)
#pragma unroll
        for (int nt = 0; nt < 8; ++nt) acc[mt][nt] = (f32x4){0.f, 0.f, 0.f, 0.f};

    const int koff = quad * 8;
#pragma unroll
    for (int kc = 0; kc < 4; ++kc) {
        int kbase = kc * 32 + koff;
        bf16x8 a0 = *(const bf16x8*)(sA + (wv * 32 + 0 + l16) * 136 + kbase);
        bf16x8 a1 = *(const bf16x8*)(sA + (wv * 32 + 16 + l16) * 136 + kbase);
#pragma unroll
        for (int nt = 0; nt < 8; ++nt) {
            bf16x8 bb = *(const bf16x8*)(sB + (nt * 16 + l16) * 136 + kbase);
            acc[0][nt] = __builtin_amdgcn_mfma_f32_16x16x32_bf16(a0, bb, acc[0][nt], 0, 0, 0);
            acc[1][nt] = __builtin_amdgcn_mfma_f32_16x16x32_bf16(a1, bb, acc[1][nt], 0, 0, 0);
        }
    }

    // epilogue: bias, bf16 store (unscaled; rs applied in f32 at agg)
#pragma unroll
    for (int mt = 0; mt < 2; ++mt) {
#pragma unroll
        for (int r = 0; r < 4; ++r) {
            int row = row0 + wv * 32 + mt * 16 + quad * 4 + r;
            if (row >= n) continue;
#pragma unroll
            for (int nt = 0; nt < 8; ++nt) {
                int col = nt * 16 + l16;
                hsb[(size_t)row * 128 + col] = f2bf(acc[mt][nt][r] + b[col]);
            }
        }
    }
}

// ---- D2: one block per 64-node bin; cell-per-thread with vectorized cell
//          load (4 independent int4), records processed from registers. ----
__global__ __launch_bounds__(256) void k_binB(const unsigned* __restrict__ gbuf,
                                              const int* __restrict__ gcnt,
                                              const int* __restrict__ aovb,
                                              const int2* __restrict__ aov,
                                              unsigned short* __restrict__ ell,
                                              int* __restrict__ cnt,
                                              float* __restrict__ rs,
                                              int2* __restrict__ ovf2,
                                              int* __restrict__ ovf2c, int n) {
    __shared__ int lcnt[BINW];
    __shared__ __align__(16) unsigned short ells[BINW * CAP];  // 5 KB
    const int tid = threadIdx.x;
    const int bin = blockIdx.x;
    const int node0 = bin * BINW;

    if (tid < BINW) lcnt[tid] = 0;
    __syncthreads();

    // thread t consumes pass-A block t's 64B cell (vector-loaded, no serial chain)
    {
        int c = gcnt[(size_t)tid * NBIN + bin];
        const int4* cell4 = (const int4*)(gbuf + ((size_t)tid * NBIN + bin) * CAPA);
        int4 q0 = cell4[0];  // 4 independent loads, all in flight together
        int4 q1 = cell4[1];
        int4 q2 = cell4[2];
        int4 q3 = cell4[3];
#define PROC(REC, J)                                              \
        if ((J) < c) {                                            \
            unsigned rec = (unsigned)(REC);                       \
            int src = rec & 0xffff;                               \
            int dlo = rec >> 16;                                  \
            int r = atomicAdd(&lcnt[dlo], 1);                     \
            if (r < CAP) {                                        \
                ells[dlo * CAP + r] = (unsigned short)src;        \
            } else {                                              \
                int k = atomicAdd(ovf2c, 1);                      \
                if (k < OVCAP) ovf2[k] = make_int2(src, node0 + dlo); \
            }                                                     \
        }
        PROC(q0.x, 0)  PROC(q0.y, 1)  PROC(q0.z, 2)  PROC(q0.w, 3)
        PROC(q1.x, 4)  PROC(q1.y, 5)  PROC(q1.z, 6)  PROC(q1.w, 7)
        PROC(q2.x, 8)  PROC(q2.y, 9)  PROC(q2.z, 10) PROC(q2.w, 11)
        PROC(q3.x, 12) PROC(q3.y, 13) PROC(q3.z, 14) PROC(q3.w, 15)
#undef PROC
    }
    // merge pass-A per-block overflow slots (expected ~0 on this graph)
    {
        int cov = aovb[tid];  // tid = passA block id (NB_A == 256)
        for (int j = 0; j < cov; ++j) {
            int2 p = aov[tid * OVB + j];
            if ((p.y >> 6) == bin) {
                int dlo = p.y & 63;
                int r = atomicAdd(&lcnt[dlo], 1);
                if (r < CAP) {
                    ells[dlo * CAP + r] = (unsigned short)p.x;
                } else {
                    int k = atomicAdd(ovf2c, 1);
                    if (k < OVCAP) ovf2[k] = make_int2(p.x, node0 + dlo);
                }
            }
        }
    }
    __syncthreads();
    // coalesced write-out: degrees + rs + 5KB of ELL rows
    if (tid < BINW) {
        int node = node0 + tid;
        cnt[node] = lcnt[tid];
        rs[node] = rsqrtf((float)(lcnt[tid] + 1));
    }
    const int4* sp = (const int4*)ells;
    int4* dp = (int4*)(ell + (size_t)node0 * CAP);
#pragma unroll
    for (int i = tid; i < BINW * CAP * 2 / 16; i += 256) dp[i] = sp[i];
}

// ---- D3: half-wave (32 lanes) per node; lane = 4 channels (ushort4 = 8B).
// out[d] = rs_d * ( rs_d*g_d + sum_{s in N(d)} rs_s*g_s ), g = hs (unscaled).
__global__ __launch_bounds__(256) void k_agg(const int* __restrict__ cnt,
                                             const float* __restrict__ rs,
                                             const unsigned short* __restrict__ ell,
                                             const int2* __restrict__ ovf2,
                                             const int* __restrict__ ovf2c,
                                             const unsigned short* __restrict__ hsb,
                                             float* __restrict__ out, int n) {
    int node = blockIdx.x * 8 + (threadIdx.x >> 5);
    if (node >= n) return;
    int lane = threadIdx.x & 31;
    int deg = cnt[node];
    float rsn = rs[node];
    int m = min(deg, CAP);

    const ushort4* hp = (const ushort4*)hsb;  // row = 32 ushort4 (256B)
    ushort4 sv = hp[(size_t)node * 32 + lane];
    float4 acc;
    acc.x = rsn * bf2f(sv.x); acc.y = rsn * bf2f(sv.y);
    acc.z = rsn * bf2f(sv.z); acc.w = rsn * bf2f(sv.w);

    const unsigned short* row = ell + (size_t)node * CAP;  // 80B/node, 16B-aligned
    int e = 0;
    for (; e + 8 <= m; e += 8) {  // 16B index load + 8 rs + 8 row gathers in flight
        us8 p = *(const us8*)(row + e);
        float w0 = rs[p[0]], w1 = rs[p[1]], w2 = rs[p[2]], w3 = rs[p[3]];
        float w4 = rs[p[4]], w5 = rs[p[5]], w6 = rs[p[6]], w7 = rs[p[7]];
        ushort4 v0 = hp[(size_t)p[0] * 32 + lane];
        ushort4 v1 = hp[(size_t)p[1] * 32 + lane];
        ushort4 v2 = hp[(size_t)p[2] * 32 + lane];
        ushort4 v3 = hp[(size_t)p[3] * 32 + lane];
        ushort4 v4 = hp[(size_t)p[4] * 32 + lane];
        ushort4 v5 = hp[(size_t)p[5] * 32 + lane];
        ushort4 v6 = hp[(size_t)p[6] * 32 + lane];
        ushort4 v7 = hp[(size_t)p[7] * 32 + lane];
        accw(acc, v0, w0); accw(acc, v1, w1); accw(acc, v2, w2); accw(acc, v3, w3);
        accw(acc, v4, w4); accw(acc, v5, w5); accw(acc, v6, w6); accw(acc, v7, w7);
    }
    if (e + 4 <= m) {
        us4 p = *(const us4*)(row + e);
        float w0 = rs[p[0]], w1 = rs[p[1]], w2 = rs[p[2]], w3 = rs[p[3]];
        ushort4 v0 = hp[(size_t)p[0] * 32 + lane];
        ushort4 v1 = hp[(size_t)p[1] * 32 + lane];
        ushort4 v2 = hp[(size_t)p[2] * 32 + lane];
        ushort4 v3 = hp[(size_t)p[3] * 32 + lane];
        accw(acc, v0, w0); accw(acc, v1, w1); accw(acc, v2, w2); accw(acc, v3, w3);
        e += 4;
    }
    for (; e < m; ++e) {
        int s = row[e];
        accw(acc, hp[(size_t)s * 32 + lane], rs[s]);
    }
    if (deg > CAP) {  // expect: never taken
        int novf = min(*ovf2c, OVCAP);
        for (int i = 0; i < novf; ++i) {
            int2 p = ovf2[i];
            if (p.y == node) {
                accw(acc, hp[(size_t)p.x * 32 + lane], rs[p.x]);
            }
        }
    }
    acc.x *= rsn; acc.y *= rsn; acc.z *= rsn; acc.w *= rsn;
    ((float4*)out)[(size_t)node * 32 + lane] = acc;
}

extern "C" void kernel_launch(void* const* d_in, const int* in_sizes, int n_in,
                              void* d_out, int out_size, void* d_ws, size_t ws_size,
                              hipStream_t stream) {
    const float* h = (const float*)d_in[0];
    const float* W = (const float*)d_in[1];
    const float* b = (const float*)d_in[2];
    const int* edges = (const int*)d_in[3];

    const int n = in_sizes[0] / IN_DIM;  // 50000 (ushort records assume n < 65536)
    const int E = in_sizes[3] / 2;       // 800000
    const int ngemm = (n + 127) / 128;   // 391 GEMM tiles
    const int nnode_pad = NBIN * BINW;   // 50176

    // workspace carve-up (float units, each region 2KB-aligned)
    size_t o = 0;
    auto carve = [&](size_t elems) {
        size_t cur = o;
        o += (elems + 511) & ~(size_t)511;
        return cur;
    };
    float* ws = (float*)d_ws;
    unsigned short* hsb = (unsigned short*)(ws + carve((size_t)n * 64));  // n*128 bf16
    unsigned* gbuf = (unsigned*)(ws + carve((size_t)NB_A * NBIN * CAPA)); // 12.8 MB
    int* gcnt = (int*)(ws + carve((size_t)NB_A * NBIN));
    int* aovb = (int*)(ws + carve(NB_A));
    int2* aov = (int2*)(ws + carve((size_t)NB_A * OVB * 2));
    int* cnt = (int*)(ws + carve(nnode_pad));
    float* rs = ws + carve(nnode_pad);
    unsigned short* ell = (unsigned short*)(ws + carve((size_t)nnode_pad * CAP / 2));
    int2* ovf2 = (int2*)(ws + carve(OVCAP * 2));
    int* ctrs = (int*)(ws + carve(2));  // [0] = ovf2c

    float* out = (float*)d_out;

    k_gb<<<ngemm + NB_A, 256, 0, stream>>>(h, W, b, hsb, n, edges, gbuf, gcnt,
                                           aovb, aov, ctrs, E, ngemm);
    k_binB<<<NBIN, 256, 0, stream>>>(gbuf, gcnt, aovb, aov, ell, cnt, rs,
                                     ovf2, ctrs, n);
    k_agg<<<(n + 7) / 8, 256, 0, stream>>>(cnt, rs, ell, ovf2, ctrs, hsb, out, n);
}